// Round 3
// baseline (1063.976 us; speedup 1.0000x reference)
//
#include <hip/hip_runtime.h>
#include <hip/hip_bf16.h>
#include <hip/hip_fp16.h>

typedef _Float16 f16;
typedef _Float16 f16x8 __attribute__((ext_vector_type(8)));
typedef float f32x4 __attribute__((ext_vector_type(4)));

#define SP 16384  // 128*128 spatial per batch
#define TPB 16    // tiles per persistent block (256 blocks * 16 = 4096 tiles)
#define XBUF 40960

// ---- transpose + cast weights to fp16, N-major: WT[n][k] = W[k][n] ----
__global__ void prep_weights(const float* __restrict__ Wq,
                             const float* __restrict__ Wkv,
                             const float* __restrict__ Wp,
                             f16* __restrict__ wqT,
                             f16* __restrict__ wkvT,
                             f16* __restrict__ wpT) {
  const int f = threadIdx.x;  // 0..511 feature (col of W)
  const int k = blockIdx.x;   // 0..255 input dim (row of W)
  wkvT[f * 256 + k] = (f16)Wkv[k * 512 + f];
  if (f < 256) {
    wqT[f * 256 + k] = (f16)Wq[k * 256 + f];
    wpT[f * 256 + k] = (f16)Wp[k * 256 + f];
  }
}

// Persistent fused kernel. Per tile: issue next-tile HBM loads early, GEMM
// (swapped-operand MFMA -> C[dk][s]), lane-local attention, projection,
// drain loads -> fp16 -> LDS buf^1 at tile end. 2 barriers/tile.
__global__ __launch_bounds__(512, 1) void fused_attn(
    const float* __restrict__ x,
    const float* __restrict__ bq,
    const float* __restrict__ bkv,
    const float* __restrict__ bp,
    const float* __restrict__ pos_bias,
    const f16* __restrict__ wqT,
    const f16* __restrict__ wkvT,
    const f16* __restrict__ wpT,
    float* __restrict__ out) {
  __shared__ f16 xs[2][5 * 16 * 256];  // 2 x 40 KB, swizzled byte ^= (row&7)<<4
  __shared__ f16 as[16 * 256];         // 8 KB attn-out tile

  const int tid = threadIdx.x;
  // staging role: row r (0..15), d-chunk q (0..31) -> d = 8q..8q+7
  const int r = tid & 15;
  const int q = tid >> 4;
  // compute role
  const int lane = tid & 63;
  const int w = tid >> 6;    // wave 0..7 -> heads 2w, 2w+1
  const int c = lane & 15;   // swapped C-layout: c = spatial index s
  const int g4 = lane >> 4;  // dk group: dk = 4*g4 + rr
  const int hA = 2 * w;

  // wave-uniform-ish scalars held in regs (small)
  float pb[2][5], bpv[2];
#pragma unroll
  for (int j = 0; j < 2; ++j) {
    bpv[j] = bp[(hA + j) * 16 + c];
#pragma unroll
    for (int t = 0; t < 5; ++t) pb[j][t] = pos_bias[(hA + j) * 5 + t];
  }

  // weight row pointers (A-operand rows: feat = head*16 + c, k-major)
  const f16* wqp0 = wqT + (hA * 16 + c) * 256;
  const f16* wqp1 = wqT + ((hA + 1) * 16 + c) * 256;
  const f16* wkp0 = wkvT + (hA * 16 + c) * 256;
  const f16* wkp1 = wkvT + ((hA + 1) * 16 + c) * 256;
  const f16* wvp0 = wkvT + (256 + hA * 16 + c) * 256;
  const f16* wvp1 = wkvT + (256 + (hA + 1) * 16 + c) * 256;
  const f16* wpp0 = wpT + (hA * 16 + c) * 256;
  const f16* wpp1 = wpT + ((hA + 1) * 16 + c) * 256;

  const int gt = blockIdx.x * TPB;

  // ---- prologue: stage tile gt into buf 0 ----
  {
    const float* xb = x + (size_t)(gt >> 10) * (5 * 256 * SP) + ((gt & 1023) << 4) + r;
#pragma unroll
    for (int t = 0; t < 5; ++t) {
      float v[8];
#pragma unroll
      for (int jj = 0; jj < 8; ++jj) v[jj] = xb[(size_t)(t * 256 + 8 * q + jj) * SP];
      f16x8 pk;
#pragma unroll
      for (int jj = 0; jj < 8; ++jj) pk[jj] = (f16)v[jj];
      const int byte = (t << 13) + (((r << 9) + (q << 4)) ^ ((r & 7) << 4));
      *(f16x8*)((char*)xs + byte) = pk;
    }
  }
  __syncthreads();

  for (int i = 0; i < TPB; ++i) {
    const int g = gt + i;
    const int b = g >> 10, s0 = (g & 1023) << 4;
    const char* lr = (const char*)xs + (i & 1) * XBUF;
    char* lw = (char*)xs + ((i & 1) ^ 1) * XBUF;
    const bool has_next = (i + 1 < TPB);

    // ---- 1. issue all next-tile loads (drained at tile end) ----
    float st[5][8];
    if (has_next) {
      const int gn = g + 1;
      const float* xn = x + (size_t)(gn >> 10) * (5 * 256 * SP) + ((gn & 1023) << 4) + r;
#pragma unroll
      for (int t = 0; t < 5; ++t)
#pragma unroll
        for (int jj = 0; jj < 8; ++jj)
          st[t][jj] = xn[(size_t)(t * 256 + 8 * q + jj) * SP];
    }

    // ---- 2. q/k/v GEMM, swapped operands: C[m=dk][n=s] ----
    f32x4 qacc[2] = {};
    f32x4 kacc[2][5] = {};
    f32x4 vacc[2][5] = {};
#pragma unroll
    for (int k0 = 0; k0 < 8; ++k0) {
      const int kk = (k0 << 5) + (g4 << 3);
      f16x8 xf[5];
#pragma unroll
      for (int t = 0; t < 5; ++t) {
        const int byte = (t << 13) + (((c << 9) + (kk << 1)) ^ ((c & 7) << 4));
        xf[t] = *(const f16x8*)(lr + byte);
      }
      const f16x8 fq0 = *(const f16x8*)(wqp0 + kk);
      const f16x8 fq1 = *(const f16x8*)(wqp1 + kk);
      const f16x8 fk0 = *(const f16x8*)(wkp0 + kk);
      const f16x8 fk1 = *(const f16x8*)(wkp1 + kk);
      const f16x8 fv0 = *(const f16x8*)(wvp0 + kk);
      const f16x8 fv1 = *(const f16x8*)(wvp1 + kk);

      qacc[0] = __builtin_amdgcn_mfma_f32_16x16x32_f16(fq0, xf[0], qacc[0], 0, 0, 0);
      qacc[1] = __builtin_amdgcn_mfma_f32_16x16x32_f16(fq1, xf[0], qacc[1], 0, 0, 0);
#pragma unroll
      for (int t = 0; t < 5; ++t) {
        kacc[0][t] = __builtin_amdgcn_mfma_f32_16x16x32_f16(fk0, xf[t], kacc[0][t], 0, 0, 0);
        kacc[1][t] = __builtin_amdgcn_mfma_f32_16x16x32_f16(fk1, xf[t], kacc[1][t], 0, 0, 0);
        vacc[0][t] = __builtin_amdgcn_mfma_f32_16x16x32_f16(fv0, xf[t], vacc[0][t], 0, 0, 0);
        vacc[1][t] = __builtin_amdgcn_mfma_f32_16x16x32_f16(fv1, xf[t], vacc[1][t], 0, 0, 0);
      }
    }

    // ---- 3. attention: lane holds q/k/v[dk=4g4+rr][s=c] ----
#pragma unroll
    for (int j = 0; j < 2; ++j) {
      const int hj = hA + j;
      float bqr[4], bkr[4], bvr[4];
#pragma unroll
      for (int rr = 0; rr < 4; ++rr) {
        bqr[rr] = bq[hj * 16 + 4 * g4 + rr];
        bkr[rr] = bkv[hj * 16 + 4 * g4 + rr];
        bvr[rr] = bkv[256 + hj * 16 + 4 * g4 + rr];
      }
      float qv[4];
#pragma unroll
      for (int rr = 0; rr < 4; ++rr) qv[rr] = qacc[j][rr] + bqr[rr];

      float sc[5];
#pragma unroll
      for (int t = 0; t < 5; ++t) {
        float p = 0.f;
#pragma unroll
        for (int rr = 0; rr < 4; ++rr) p += qv[rr] * (kacc[j][t][rr] + bkr[rr]);
        p += __shfl_xor(p, 16);
        p += __shfl_xor(p, 32);
        sc[t] = p * 4.0f + pb[j][t];  // /temperature (=0.25) + pos_bias
      }
      float m = sc[0];
#pragma unroll
      for (int t = 1; t < 5; ++t) m = fmaxf(m, sc[t]);
      float l = 0.f;
#pragma unroll
      for (int t = 0; t < 5; ++t) { sc[t] = __expf(sc[t] - m); l += sc[t]; }
      const float inv = 1.0f / l;

#pragma unroll
      for (int rr = 0; rr < 4; ++rr) {
        float o = 0.f;
#pragma unroll
        for (int t = 0; t < 5; ++t) o += sc[t] * (vacc[j][t][rr] + bvr[rr]);
        // write attn-out: as[row=s=c][feat = hj*16 + 4g4+rr]
        const int byte = ((c << 9) + ((hj * 16 + 4 * g4 + rr) << 1)) ^ ((c & 7) << 4);
        *(f16*)((char*)as + byte) = (f16)(o * inv);
      }
    }
    __syncthreads();  // B1: as visible

    // ---- 4. projection (normal operand order): C[m=s][n=feat_out] ----
    f32x4 facc[2] = {};
#pragma unroll
    for (int k0 = 0; k0 < 8; ++k0) {
      const int kk = (k0 << 5) + (g4 << 3);
      const int byte = (((c << 9) + (kk << 1)) ^ ((c & 7) << 4));
      const f16x8 af = *(const f16x8*)((const char*)as + byte);
      const f16x8 f0 = *(const f16x8*)(wpp0 + kk);
      const f16x8 f1 = *(const f16x8*)(wpp1 + kk);
      facc[0] = __builtin_amdgcn_mfma_f32_16x16x32_f16(af, f0, facc[0], 0, 0, 0);
      facc[1] = __builtin_amdgcn_mfma_f32_16x16x32_f16(af, f1, facc[1], 0, 0, 0);
    }

    // ---- 5. store: out[b, dg, s0 + 4*g4 .. +3] ----
#pragma unroll
    for (int j = 0; j < 2; ++j) {
      const int dg = (hA + j) * 16 + c;
      f32x4 vs = facc[j];
#pragma unroll
      for (int rr = 0; rr < 4; ++rr) vs[rr] += bpv[j];
      float* dst = out + ((size_t)b * 256 + dg) * SP + s0 + (g4 << 2);
      *(f32x4*)dst = vs;
    }

    // ---- 6. drain staged loads -> fp16 -> buf^1 ----
    if (has_next) {
#pragma unroll
      for (int t = 0; t < 5; ++t) {
        f16x8 pk;
#pragma unroll
        for (int jj = 0; jj < 8; ++jj) pk[jj] = (f16)st[t][jj];
        const int byte = (t << 13) + (((r << 9) + (q << 4)) ^ ((r & 7) << 4));
        *(f16x8*)(lw + byte) = pk;
      }
    }
    __syncthreads();  // B2: as reads done; buf^1 ready for next GEMM
  }
}

extern "C" void kernel_launch(void* const* d_in, const int* in_sizes, int n_in,
                              void* d_out, int out_size, void* d_ws, size_t ws_size,
                              hipStream_t stream) {
  const float* x   = (const float*)d_in[0];
  const float* Wq  = (const float*)d_in[1];
  const float* bq  = (const float*)d_in[2];
  const float* Wkv = (const float*)d_in[3];
  const float* bkv = (const float*)d_in[4];
  const float* Wp  = (const float*)d_in[5];
  const float* bp  = (const float*)d_in[6];
  const float* pos = (const float*)d_in[7];

  f16* wqT  = (f16*)d_ws;            // 256*256
  f16* wkvT = wqT + 256 * 256;       // 512*256
  f16* wpT  = wkvT + 512 * 256;      // 256*256

  prep_weights<<<256, 512, 0, stream>>>(Wq, Wkv, Wp, wqT, wkvT, wpT);
  fused_attn<<<256, 512, 0, stream>>>(x, bq, bkv, bp, pos, wqT, wkvT, wpT,
                                      (float*)d_out);
}

// Round 4
// 353.226 us; speedup vs baseline: 3.0122x; 3.0122x over previous
//
#include <hip/hip_runtime.h>
#include <hip/hip_bf16.h>
#include <hip/hip_fp16.h>

typedef _Float16 f16;
typedef _Float16 f16x8 __attribute__((ext_vector_type(8)));
typedef float f32x4 __attribute__((ext_vector_type(4)));

#define SP 16384  // 128*128 spatial per batch
#define TPB 16    // tiles per persistent block (256 blocks * 16 = 4096 tiles)

__global__ void prep_weights(const float* __restrict__ Wq,
                             const float* __restrict__ Wkv,
                             const float* __restrict__ Wp,
                             f16* __restrict__ wqT,
                             f16* __restrict__ wkvT,
                             f16* __restrict__ wpT) {
  const int f = threadIdx.x;
  const int k = blockIdx.x;
  wkvT[f * 256 + k] = (f16)Wkv[k * 512 + f];
  if (f < 256) {
    wqT[f * 256 + k] = (f16)Wq[k * 256 + f];
    wpT[f * 256 + k] = (f16)Wp[k * 256 + f];
  }
}

// Persistent fused kernel. Staging via global_load_lds (no VGPR staging):
// sb (80KB f32, [td][row]) <- HBM async; convert -> fb (40KB f16, tiled
// [t][k0][c][g4]); k-loop (swapped MFMA, C[dk][s]); lane-local attention;
// projection; store. 3 barriers/tile.
__global__ __launch_bounds__(512, 1) void fused_attn(
    const float* __restrict__ x,
    const float* __restrict__ bq,
    const float* __restrict__ bkv,
    const float* __restrict__ bp,
    const float* __restrict__ pos_bias,
    const f16* __restrict__ wqT,
    const f16* __restrict__ wkvT,
    const f16* __restrict__ wpT,
    float* __restrict__ out) {
  __shared__ float sb[5 * 256 * 16];  // 80 KB staging: sb[td][row], td = t*256+d
  __shared__ f16 fb[5 * 16 * 256];    // 40 KB tile: [t][k0][c(row)][g4] 16B blocks
  __shared__ f16 as_[16 * 256];       // 8 KB attn-out, tiled [k0][c][g4^c&3]

  const int tid = threadIdx.x;
  const int lane = tid & 63;
  const int w = tid >> 6;    // wave 0..7 -> heads 2w, 2w+1
  const int c = lane & 15;   // fragment row (spatial s) / B-col
  const int g4 = lane >> 4;  // k-group
  const int hA = 2 * w;

  // ---- hoisted per-lane constants ----
  float pb[2][5], bpv[2], bqr[2][4], bkr[2][4], bvr[2][4];
#pragma unroll
  for (int j = 0; j < 2; ++j) {
    const int hj = hA + j;
    bpv[j] = bp[hj * 16 + c];
#pragma unroll
    for (int t = 0; t < 5; ++t) pb[j][t] = pos_bias[hj * 5 + t];
#pragma unroll
    for (int rr = 0; rr < 4; ++rr) {
      bqr[j][rr] = bq[hj * 16 + 4 * g4 + rr];
      bkr[j][rr] = bkv[hj * 16 + 4 * g4 + rr];
      bvr[j][rr] = bkv[256 + hj * 16 + 4 * g4 + rr];
    }
  }

  const f16* wqp0 = wqT + (hA * 16 + c) * 256;
  const f16* wqp1 = wqT + ((hA + 1) * 16 + c) * 256;
  const f16* wkp0 = wkvT + (hA * 16 + c) * 256;
  const f16* wkp1 = wkvT + ((hA + 1) * 16 + c) * 256;
  const f16* wvp0 = wkvT + (256 + hA * 16 + c) * 256;
  const f16* wvp1 = wkvT + (256 + (hA + 1) * 16 + c) * 256;
  const f16* wpp0 = wpT + (hA * 16 + c) * 256;
  const f16* wpp1 = wpT + ((hA + 1) * 16 + c) * 256;

  const int gt = blockIdx.x * TPB;
  const int p16 = lane >> 2;   // td offset within instr (0..15)
  const int rq4 = (lane & 3) << 2;  // starting row (4 floats along s)

  // stage tile g: 10 global_load_lds(16B) per wave -> sb linear
  auto stage = [&](int g) {
    const float* xb = x + (size_t)(g >> 10) * (5 * 256 * SP) + ((g & 1023) << 4);
#pragma unroll
    for (int n = 0; n < 10; ++n) {
      const int td0 = (w * 10 + n) * 16;
      const float* src = xb + (size_t)(td0 + p16) * SP + rq4;
      __builtin_amdgcn_global_load_lds(
          (const void __attribute__((address_space(1)))*)src,
          (void __attribute__((address_space(3)))*)&sb[td0 * 16], 16, 0, 0);
    }
  };

  // convert sb (f32 [td][row]) -> fb (f16 tiled). 5 passes, paired d writes.
  auto convert = [&]() {
#pragma unroll
    for (int p5 = 0; p5 < 5; ++p5) {
      const int task = p5 * 512 + tid;   // 2560 tasks = (duo 640) x (rq 4)
      const int duo = task >> 2, rq = task & 3;
      const int t = duo >> 7, d2 = duo & 127;
      const int td = t * 256 + (d2 << 1);
      const f32x4 va = *(const f32x4*)&sb[(td << 4) + (rq << 2)];
      const f32x4 vb = *(const f32x4*)&sb[((td + 1) << 4) + (rq << 2)];
      const int d = d2 << 1;
      const int bb = (t << 13) + ((d >> 5) << 10) + (((d >> 3) & 3) << 4) + ((d & 7) << 1);
#pragma unroll
      for (int rr = 0; rr < 4; ++rr) {
        const int row = (rq << 2) + rr;
        union { f16 h[2]; unsigned u; } pk;
        pk.h[0] = (f16)va[rr];
        pk.h[1] = (f16)vb[rr];
        *(unsigned*)((char*)fb + bb + (row << 6)) = pk.u;
      }
    }
  };

  // ---- prologue ----
  stage(gt);
  __syncthreads();   // implicit vmcnt drain: sb ready
  convert();
  __syncthreads();
  stage(gt + 1);

  for (int i = 0; i < TPB; ++i) {
    const int g = gt + i;
    const int b = g >> 10, s0 = (g & 1023) << 4;

    // ---- q/k/v GEMM, swapped operands: C[m=dk][n=s] ----
    f32x4 qacc[2] = {};
    f32x4 kacc[2][5] = {};
    f32x4 vacc[2][5] = {};
    const char* fbp = (const char*)fb;
#pragma unroll 1
    for (int k0 = 0; k0 < 8; ++k0) {
      const int base = (k0 << 10) + (c << 6) + (g4 << 4);
      f16x8 xf[5];
#pragma unroll
      for (int t = 0; t < 5; ++t) xf[t] = *(const f16x8*)(fbp + (t << 13) + base);
      const int kk = (k0 << 5) + (g4 << 3);
      const f16x8 fq0 = *(const f16x8*)(wqp0 + kk);
      const f16x8 fq1 = *(const f16x8*)(wqp1 + kk);
      const f16x8 fk0 = *(const f16x8*)(wkp0 + kk);
      const f16x8 fk1 = *(const f16x8*)(wkp1 + kk);
      const f16x8 fv0 = *(const f16x8*)(wvp0 + kk);
      const f16x8 fv1 = *(const f16x8*)(wvp1 + kk);

      qacc[0] = __builtin_amdgcn_mfma_f32_16x16x32_f16(fq0, xf[0], qacc[0], 0, 0, 0);
      qacc[1] = __builtin_amdgcn_mfma_f32_16x16x32_f16(fq1, xf[0], qacc[1], 0, 0, 0);
#pragma unroll
      for (int t = 0; t < 5; ++t) {
        kacc[0][t] = __builtin_amdgcn_mfma_f32_16x16x32_f16(fk0, xf[t], kacc[0][t], 0, 0, 0);
        kacc[1][t] = __builtin_amdgcn_mfma_f32_16x16x32_f16(fk1, xf[t], kacc[1][t], 0, 0, 0);
        vacc[0][t] = __builtin_amdgcn_mfma_f32_16x16x32_f16(fv0, xf[t], vacc[0][t], 0, 0, 0);
        vacc[1][t] = __builtin_amdgcn_mfma_f32_16x16x32_f16(fv1, xf[t], vacc[1][t], 0, 0, 0);
      }
    }
    __syncthreads();  // B1: fb reads done (also drains in-flight gll)

    // ---- attention: lane holds q/k/v[dk=4g4+rr][s=c] ----
#pragma unroll
    for (int j = 0; j < 2; ++j) {
      float qv[4];
#pragma unroll
      for (int rr = 0; rr < 4; ++rr) qv[rr] = qacc[j][rr] + bqr[j][rr];
      float sc[5];
#pragma unroll
      for (int t = 0; t < 5; ++t) {
        float p = 0.f;
#pragma unroll
        for (int rr = 0; rr < 4; ++rr) p += qv[rr] * (kacc[j][t][rr] + bkr[j][rr]);
        p += __shfl_xor(p, 16);
        p += __shfl_xor(p, 32);
        sc[t] = p * 4.0f + pb[j][t];  // /temperature (=0.25) + pos_bias
      }
      float m = sc[0];
#pragma unroll
      for (int t = 1; t < 5; ++t) m = fmaxf(m, sc[t]);
      float l = 0.f;
#pragma unroll
      for (int t = 0; t < 5; ++t) { sc[t] = __expf(sc[t] - m); l += sc[t]; }
      const float inv = 1.0f / l;
      float oo[4];
#pragma unroll
      for (int rr = 0; rr < 4; ++rr) {
        float o = 0.f;
#pragma unroll
        for (int t = 0; t < 5; ++t) o += sc[t] * (vacc[j][t][rr] + bvr[j][rr]);
        oo[rr] = o * inv;
      }
      // write as_ tiled: feat = hj*16 + 4g4 + rr, row = c
      const int hj = hA + j;
#pragma unroll
      for (int pr = 0; pr < 2; ++pr) {
        const int feat0 = hj * 16 + 4 * g4 + 2 * pr;
        const int byte = ((feat0 >> 5) << 10) + (c << 6) +
                         ((((feat0 >> 3) & 3) ^ (c & 3)) << 4) + ((feat0 & 7) << 1);
        union { f16 h[2]; unsigned u; } pk;
        pk.h[0] = (f16)oo[2 * pr];
        pk.h[1] = (f16)oo[2 * pr + 1];
        *(unsigned*)((char*)as_ + byte) = pk.u;
      }
    }
    __syncthreads();  // B2: as_ visible

    // ---- convert next tile (overlaps nothing LDS-conflicting with proj) ----
    if (i + 1 < TPB) convert();

    // ---- projection: attn_out[16s x 256] @ Wp -> C[m=s][n=feat_out] ----
    f32x4 facc[2] = {};
#pragma unroll 1
    for (int k0 = 0; k0 < 8; ++k0) {
      const f16x8 af = *(const f16x8*)((const char*)as_ + (k0 << 10) + (c << 6) +
                                       ((g4 ^ (c & 3)) << 4));
      const int kk = (k0 << 5) + (g4 << 3);
      const f16x8 f0 = *(const f16x8*)(wpp0 + kk);
      const f16x8 f1 = *(const f16x8*)(wpp1 + kk);
      facc[0] = __builtin_amdgcn_mfma_f32_16x16x32_f16(af, f0, facc[0], 0, 0, 0);
      facc[1] = __builtin_amdgcn_mfma_f32_16x16x32_f16(af, f1, facc[1], 0, 0, 0);
    }

    // ---- store: out[b, dg, s0 + 4*g4 + rr] ----
#pragma unroll
    for (int j = 0; j < 2; ++j) {
      const int dg = (hA + j) * 16 + c;
      f32x4 vs = facc[j];
#pragma unroll
      for (int rr = 0; rr < 4; ++rr) vs[rr] += bpv[j];
      float* dst = out + ((size_t)b * 256 + dg) * SP + s0 + (g4 << 2);
      *(f32x4*)dst = vs;
    }

    __syncthreads();  // B3: fb writes visible; as_ reads done; sb free

    if (i + 2 < TPB) stage(g + 2);
  }
}

extern "C" void kernel_launch(void* const* d_in, const int* in_sizes, int n_in,
                              void* d_out, int out_size, void* d_ws, size_t ws_size,
                              hipStream_t stream) {
  const float* x   = (const float*)d_in[0];
  const float* Wq  = (const float*)d_in[1];
  const float* bq  = (const float*)d_in[2];
  const float* Wkv = (const float*)d_in[3];
  const float* bkv = (const float*)d_in[4];
  const float* Wp  = (const float*)d_in[5];
  const float* bp  = (const float*)d_in[6];
  const float* pos = (const float*)d_in[7];

  f16* wqT  = (f16*)d_ws;            // 256*256
  f16* wkvT = wqT + 256 * 256;       // 512*256
  f16* wpT  = wkvT + 512 * 256;      // 256*256

  prep_weights<<<256, 512, 0, stream>>>(Wq, Wkv, Wp, wqT, wkvT, wpT);
  fused_attn<<<256, 512, 0, stream>>>(x, bq, bkv, bp, pos, wqT, wkvT, wpT,
                                      (float*)d_out);
}